// Round 1
// baseline (3058.809 us; speedup 1.0000x reference)
//
#include <hip/hip_runtime.h>
#include <math.h>

// DecoupledRouterPool: dense per-class 3-layer MLP + LN + exact GELU + cosine
// geometry vs normalized anchors + argmin routing.
//
// Round 0: fp32 VALU baseline (no fp32 MFMA exists on CDNA4).
// Fused kernel: grid (32 token-tiles, 100 classes), 256 threads, BT=64 tokens.
// H stays transposed in LDS [256][68]; W chunks reg-staged k-tiled (KT=16),
// loads issued before the FMA chunk (T14 split) to hide HBM latency.
// dist = sqrt(2-2s), s = (t . a_hat)/||t||  (both unit => never materialize t).

#define NTOK 2048
#define NCLS 100
#define IND  512
#define HIDD 256
#define OUTD 512
#define BT   64
#define KT   16
#define SA   68    // LDS row stride for A-operands (tokens dim), 16B-aligned rows
#define SWS  260   // LDS row stride for W chunk (out dim), 16B-aligned rows

__device__ __forceinline__ float4 ld4(const float* p) { return *(const float4*)p; }

__device__ __forceinline__ void loadW4(float4 wr[4], const float* __restrict__ g, int k0) {
#pragma unroll
  for (int i = 0; i < 4; ++i) wr[i] = ld4(g + k0 + 4 * i);
}

__device__ __forceinline__ void storeW4(float* sW, const float4 wr[4], int t) {
#pragma unroll
  for (int i = 0; i < 4; ++i) {
    sW[(4 * i + 0) * SWS + t] = wr[i].x;
    sW[(4 * i + 1) * SWS + t] = wr[i].y;
    sW[(4 * i + 2) * SWS + t] = wr[i].z;
    sW[(4 * i + 3) * SWS + t] = wr[i].w;
  }
}

__device__ __forceinline__ void storeX4(float* sX, const float4 xr, int xtok, int xkh) {
  sX[(xkh * 4 + 0) * SA + xtok] = xr.x;
  sX[(xkh * 4 + 1) * SA + xtok] = xr.y;
  sX[(xkh * 4 + 2) * SA + xtok] = xr.z;
  sX[(xkh * 4 + 3) * SA + xtok] = xr.w;
}

// One KT-deep FMA chunk: A[k][token] (broadcast per half-wave), W[k][o] (coalesced b128).
__device__ __forceinline__ void fma_chunk(const float* __restrict__ A, const float* __restrict__ sW,
                                          int ty8, int o_lo, int o_hi, float acc[8][8]) {
#pragma unroll
  for (int k = 0; k < KT; ++k) {
    const float* a = A + k * SA + ty8;
    float4 t0 = ld4(a);
    float4 t1 = ld4(a + 4);
    const float* w = sW + k * SWS;
    float4 w0 = ld4(w + o_lo);
    float4 w1 = ld4(w + o_hi);
    float tv[8] = {t0.x, t0.y, t0.z, t0.w, t1.x, t1.y, t1.z, t1.w};
    float wv[8] = {w0.x, w0.y, w0.z, w0.w, w1.x, w1.y, w1.z, w1.w};
#pragma unroll
    for (int j = 0; j < 8; ++j)
#pragma unroll
      for (int i = 0; i < 8; ++i)
        acc[j][i] = fmaf(tv[j], wv[i], acc[j][i]);
  }
}

// Generic phase: A already resident in LDS (sH), W staged chunk-by-chunk.
template <int NC>
__device__ __forceinline__ void gemm_phase(const float* __restrict__ gRow, const float* __restrict__ A,
                                           float* sW, int tid, int ty8, int o_lo, int o_hi,
                                           float acc[8][8]) {
  float4 wr[4];
  loadW4(wr, gRow, 0);
  __syncthreads();          // previous users of sW (and sH writers) done
  storeW4(sW, wr, tid);
  __syncthreads();
#pragma unroll 1
  for (int kc = 0; kc < NC; ++kc) {
    if (kc + 1 < NC) loadW4(wr, gRow, (kc + 1) * KT);   // issue early: lands during fma
    fma_chunk(A + kc * KT * SA, sW, ty8, o_lo, o_hi, acc);
    if (kc + 1 < NC) {
      __syncthreads();
      storeW4(sW, wr, tid);
      __syncthreads();
    }
  }
}

// Phase 1: also stages X tile (transposed) chunk-by-chunk.
__device__ __forceinline__ void gemm_phase1(const float* __restrict__ gWrow, const float* __restrict__ gXrow,
                                            float* sW, float* sX, int tid, int xtok, int xkh,
                                            int ty8, int o_lo, int o_hi, float acc[8][8]) {
  float4 wr[4];
  float4 xr;
  loadW4(wr, gWrow, 0);
  xr = ld4(gXrow);
  __syncthreads();
  storeW4(sW, wr, tid);
  storeX4(sX, xr, xtok, xkh);
  __syncthreads();
#pragma unroll 1
  for (int kc = 0; kc < IND / KT; ++kc) {
    if (kc + 1 < IND / KT) {
      loadW4(wr, gWrow, (kc + 1) * KT);
      xr = ld4(gXrow + (kc + 1) * KT);
    }
    fma_chunk(sX, sW, ty8, o_lo, o_hi, acc);
    if (kc + 1 < IND / KT) {
      __syncthreads();
      storeW4(sW, wr, tid);
      storeX4(sX, xr, xtok, xkh);
      __syncthreads();
    }
  }
}

// bias add + LayerNorm (ddof=0) + exact GELU, then store transposed into sH.
__device__ __forceinline__ void ln_gelu_store(float acc[8][8], const float* __restrict__ bias,
                                              const float* __restrict__ gam, const float* __restrict__ bet,
                                              int cb, float* sH, int ty8, int o_lo, int o_hi) {
  float4 q0 = ld4(bias + cb + o_lo), q1 = ld4(bias + cb + o_hi);
  float bv[8] = {q0.x, q0.y, q0.z, q0.w, q1.x, q1.y, q1.z, q1.w};
  float4 g0 = ld4(gam + cb + o_lo), g1q = ld4(gam + cb + o_hi);
  float gv[8] = {g0.x, g0.y, g0.z, g0.w, g1q.x, g1q.y, g1q.z, g1q.w};
  float4 e0 = ld4(bet + cb + o_lo), e1 = ld4(bet + cb + o_hi);
  float ev[8] = {e0.x, e0.y, e0.z, e0.w, e1.x, e1.y, e1.z, e1.w};

  float sum[8], ssq[8];
#pragma unroll
  for (int j = 0; j < 8; ++j) {
    float s = 0.f, q = 0.f;
#pragma unroll
    for (int i = 0; i < 8; ++i) {
      float v = acc[j][i] + bv[i];
      acc[j][i] = v;
      s += v;
      q += v * v;
    }
    sum[j] = s;
    ssq[j] = q;
  }
  // reduce over the 32 lanes sharing this token group (xor<=16 stays in half-wave)
#pragma unroll
  for (int m = 1; m <= 16; m <<= 1) {
#pragma unroll
    for (int j = 0; j < 8; ++j) {
      sum[j] += __shfl_xor(sum[j], m, 64);
      ssq[j] += __shfl_xor(ssq[j], m, 64);
    }
  }
#pragma unroll
  for (int j = 0; j < 8; ++j) {
    float mu = sum[j] * (1.f / HIDD);
    float var = ssq[j] * (1.f / HIDD) - mu * mu;
    float rs = rsqrtf(var + 1e-5f);
#pragma unroll
    for (int i = 0; i < 8; ++i) {
      float v = (acc[j][i] - mu) * rs * gv[i] + ev[i];
      acc[j][i] = 0.5f * v * (1.f + erff(v * 0.70710678118654752f));
    }
  }
  // store transposed: sH[o][token], 8 consecutive tokens => 2x b128 per o
#pragma unroll
  for (int i = 0; i < 8; ++i) {
    int o = (i < 4) ? (o_lo + i) : (o_hi + (i - 4));
    float4 p0, p1;
    p0.x = acc[0][i]; p0.y = acc[1][i]; p0.z = acc[2][i]; p0.w = acc[3][i];
    p1.x = acc[4][i]; p1.y = acc[5][i]; p1.z = acc[6][i]; p1.w = acc[7][i];
    *(float4*)(sH + o * SA + ty8) = p0;
    *(float4*)(sH + o * SA + ty8 + 4) = p1;
  }
}

extern "C" __global__ void __launch_bounds__(256)
moe_fused_f32(const float* __restrict__ x, const float* __restrict__ W1, const float* __restrict__ b1,
              const float* __restrict__ g1, const float* __restrict__ be1,
              const float* __restrict__ W2, const float* __restrict__ b2,
              const float* __restrict__ g2, const float* __restrict__ be2,
              const float* __restrict__ W3, const float* __restrict__ b3,
              const float* __restrict__ anchors,
              float* __restrict__ out_dist, float* __restrict__ out_sim) {
  __shared__ __align__(16) float sW[KT * SWS];   // 16.6 KB
  __shared__ __align__(16) float sX[KT * SA];    //  4.4 KB
  __shared__ __align__(16) float sH[HIDD * SA];  // 69.6 KB
  __shared__ float sRed[4];

  const int tid = threadIdx.x;
  const int tx = tid & 31, ty = tid >> 5;
  const int ty8 = ty * 8;
  const int o_lo = 4 * tx, o_hi = 128 + 4 * tx;
  const int c = blockIdx.y;
  const int tb = blockIdx.x * BT;

  // anchor 1/||a|| (reference applies no epsilon)
  {
    float v0 = anchors[c * OUTD + tid];
    float v1 = anchors[c * OUTD + 256 + tid];
    float aa = v0 * v0 + v1 * v1;
#pragma unroll
    for (int m = 1; m <= 32; m <<= 1) aa += __shfl_xor(aa, m, 64);
    if ((tid & 63) == 0) sRed[tid >> 6] = aa;
  }
  __syncthreads();
  const float rinv = rsqrtf(sRed[0] + sRed[1] + sRed[2] + sRed[3]);

  float acc[8][8];

  // ---------------- phase 1: h1 = x . W1^T ----------------
#pragma unroll
  for (int j = 0; j < 8; ++j)
#pragma unroll
    for (int i = 0; i < 8; ++i) acc[j][i] = 0.f;

  gemm_phase1(W1 + (size_t)(c * HIDD + tid) * IND,
              x + (size_t)(tb + (tid & 63)) * IND + (tid >> 6) * 4,
              sW, sX, tid, tid & 63, tid >> 6, ty8, o_lo, o_hi, acc);
  ln_gelu_store(acc, b1, g1, be1, c * HIDD, sH, ty8, o_lo, o_hi);

  // ---------------- phase 2: h2 = h1n . W2^T ----------------
#pragma unroll
  for (int j = 0; j < 8; ++j)
#pragma unroll
    for (int i = 0; i < 8; ++i) acc[j][i] = 0.f;

  gemm_phase<HIDD / KT>(W2 + (size_t)(c * HIDD + tid) * HIDD, sH, sW, tid, ty8, o_lo, o_hi, acc);
  __syncthreads();  // all waves done reading sH before overwrite
  ln_gelu_store(acc, b2, g2, be2, c * HIDD, sH, ty8, o_lo, o_hi);

  // ---------------- phase 3: t = h2n . W3^T (+b3), two 256-wide o-passes ----------------
  float pdot[8], psq[8];
#pragma unroll
  for (int j = 0; j < 8; ++j) { pdot[j] = 0.f; psq[j] = 0.f; }

#pragma unroll 1
  for (int p = 0; p < 2; ++p) {
#pragma unroll
    for (int j = 0; j < 8; ++j)
#pragma unroll
      for (int i = 0; i < 8; ++i) acc[j][i] = 0.f;

    gemm_phase<HIDD / KT>(W3 + (size_t)(c * OUTD + p * 256 + tid) * HIDD, sH, sW, tid, ty8, o_lo, o_hi, acc);

    const int ob = c * OUTD + p * 256;
    float4 q0 = ld4(b3 + ob + o_lo), q1 = ld4(b3 + ob + o_hi);
    float bv[8] = {q0.x, q0.y, q0.z, q0.w, q1.x, q1.y, q1.z, q1.w};
    float4 a0 = ld4(anchors + ob + o_lo), a1 = ld4(anchors + ob + o_hi);
    float av[8] = {a0.x * rinv, a0.y * rinv, a0.z * rinv, a0.w * rinv,
                   a1.x * rinv, a1.y * rinv, a1.z * rinv, a1.w * rinv};
#pragma unroll
    for (int j = 0; j < 8; ++j)
#pragma unroll
      for (int i = 0; i < 8; ++i) {
        float t = acc[j][i] + bv[i];
        pdot[j] = fmaf(t, av[i], pdot[j]);
        psq[j] = fmaf(t, t, psq[j]);
      }
  }

  // reduce per-token partials over the 32 o-lanes
#pragma unroll
  for (int m = 1; m <= 16; m <<= 1) {
#pragma unroll
    for (int j = 0; j < 8; ++j) {
      pdot[j] += __shfl_xor(pdot[j], m, 64);
      psq[j] += __shfl_xor(psq[j], m, 64);
    }
  }
  if (tx < 8) {
    float pd = 0.f, pq = 1.f;
#pragma unroll
    for (int j = 0; j < 8; ++j)
      if (tx == j) { pd = pdot[j]; pq = psq[j]; }
    const int b = tb + ty8 + tx;
    float s = pd * rsqrtf(pq);                       // t_hat . a_hat
    float d = sqrtf(fmaxf(2.f - 2.f * s, 0.f));      // ||t_hat - a_hat||
    out_dist[(size_t)b * NCLS + c] = d;
    out_sim[(size_t)b * NCLS + c] = s;
  }
}

extern "C" __global__ void __launch_bounds__(256)
argmin_routed(const float* __restrict__ dist, float* __restrict__ routed) {
  int b = blockIdx.x * blockDim.x + threadIdx.x;
  if (b >= NTOK) return;
  const float* d = dist + (size_t)b * NCLS;
  float best = d[0];
  int bi = 0;
#pragma unroll 1
  for (int cc = 1; cc < NCLS; ++cc) {
    float v = d[cc];
    if (v < best) { best = v; bi = cc; }  // strict '<' => first-index ties, matches argmin
  }
  routed[b] = (float)bi;
}

extern "C" void kernel_launch(void* const* d_in, const int* in_sizes, int n_in,
                              void* d_out, int out_size, void* d_ws, size_t ws_size,
                              hipStream_t stream) {
  const float* x = (const float*)d_in[0];
  const float* W1 = (const float*)d_in[1];
  const float* b1 = (const float*)d_in[2];
  const float* g1 = (const float*)d_in[3];
  const float* be1 = (const float*)d_in[4];
  const float* W2 = (const float*)d_in[5];
  const float* b2 = (const float*)d_in[6];
  const float* g2 = (const float*)d_in[7];
  const float* be2 = (const float*)d_in[8];
  const float* W3 = (const float*)d_in[9];
  const float* b3 = (const float*)d_in[10];
  const float* anchors = (const float*)d_in[11];

  float* out = (float*)d_out;
  float* out_routed = out;                       // [2048] as float values
  float* out_dist = out + NTOK;                  // [2048,100]
  float* out_sim = out + NTOK + NTOK * NCLS;     // [2048,100]

  dim3 grid(NTOK / BT, NCLS);
  moe_fused_f32<<<grid, 256, 0, stream>>>(x, W1, b1, g1, be1, W2, b2, g2, be2, W3, b3,
                                          anchors, out_dist, out_sim);
  argmin_routed<<<NTOK / 256, 256, 0, stream>>>(out_dist, out_routed);
}

// Round 4
// 714.991 us; speedup vs baseline: 4.2781x; 4.2781x over previous
//
#include <hip/hip_runtime.h>
#include <math.h>

// DecoupledRouterPool — split-precision f16 MFMA implementation.
//
// fp32 = hi(f16) + lo(f16) via RTZ split; each GEMM = 3 MFMA products
// (hh, hl, lh) accumulated in fp32 AGPRs -> ~fp32 accuracy at f16 MFMA rate.
//
// Pre-pass kernels write x and W1/W2/W3 as hi/lo f16 tiles in MFMA fragment
// lane order into d_ws. Main kernel: block = (class, 64 tokens), 4 waves,
// C = W . act^T (rows = out-dim, cols = token). Layer transitions do
// bias+LN+exact-GELU and rebuild next-layer B-fragments fully in-register
// (cvt_pkrtz + shfl_xor(32) half exchange), written to LDS as b128.
// K-loops are barrier-free: A-frags direct from ws (L2), B-frags from LDS.
//
// R3 fix: the shfl_xor(32) half-exchange selector was inverted — each lane
// exchanged the half it KEEPS instead of the half the partner NEEDS, so both
// lane groups got identical fragments and rows 4..11 of every k-subtile were
// dropped. Now: send = g ? P[4kt+0..1] : P[4kt+2..3]; g=0 slots=[own01,recv],
// g=1 slots=[recv,own23]  => slot j of group g holds h = kT*16 + g*8 + j.
//
// Fallback: if ws_size < ~129 MB, run the (validated) fp32 VALU path.

#define NTOK 2048
#define NCLS 100
#define IND  512
#define HIDD 256
#define OUTD 512

typedef _Float16 half8 __attribute__((ext_vector_type(8)));
typedef __fp16 half2v __attribute__((ext_vector_type(2)));
typedef float f32x16 __attribute__((ext_vector_type(16)));

#define WSX_HALVES 2097152          // 2048*512*2 (hi+lo)
#define CLS_STRIDE 655360           // 640 tile-pairs * 1024 halves
#define W2_OFF     262144           // 256 tiles * 1024
#define W3_OFF     393216           // 384 tiles * 1024
#define WS_NEED    ((size_t)(WSX_HALVES + 100 * CLS_STRIDE) * 2)

__device__ __forceinline__ unsigned h2u(half2v h) {
  union { half2v h; unsigned u; } t; t.h = h; return t.u;
}
__device__ __forceinline__ half8 u4h8(unsigned a, unsigned b, unsigned c, unsigned d) {
  union { unsigned u[4]; half8 h; } t; t.u[0] = a; t.u[1] = b; t.u[2] = c; t.u[3] = d; return t.h;
}
__device__ __forceinline__ f32x16 fzero16() {
  f32x16 z;
#pragma unroll
  for (int i = 0; i < 16; ++i) z[i] = 0.f;
  return z;
}

// ---------------------------------------------------------------------------
// Pre-pass: split fp32 -> hi/lo f16 fragment tiles.
// Tile = 32 rows x 16 k, lane l holds [row = l&31][k = (l>>5)*8 + 0..7],
// stored as 512 halves (hi) + 512 halves (lo) at tileIdx*1024.
// (The within-k16 slot->k mapping is self-canceling as long as A and B use
// the same mapping — which ws tiles and the lnGeluFrag rebuild both do.)
// ---------------------------------------------------------------------------
__device__ __forceinline__ void splitStore8(const float* __restrict__ src, _Float16* __restrict__ dst) {
  float4 f0 = *(const float4*)src, f1 = *(const float4*)(src + 4);
  float f[8] = {f0.x, f0.y, f0.z, f0.w, f1.x, f1.y, f1.z, f1.w};
  unsigned H[4], L[4];
#pragma unroll
  for (int i = 0; i < 4; ++i) {
    half2v ph = __builtin_amdgcn_cvt_pkrtz(f[2*i], f[2*i+1]);
    half2v pl = __builtin_amdgcn_cvt_pkrtz(f[2*i] - (float)ph[0], f[2*i+1] - (float)ph[1]);
    H[i] = h2u(ph); L[i] = h2u(pl);
  }
  *(half8*)dst = u4h8(H[0], H[1], H[2], H[3]);
  *(half8*)(dst + 512) = u4h8(L[0], L[1], L[2], L[3]);
}

extern "C" __global__ void __launch_bounds__(256)
split_x_k(const float* __restrict__ x, _Float16* __restrict__ wsx) {
  int tid = threadIdx.x, lane = tid & 63;
  int wid = blockIdx.x * 4 + (tid >> 6);     // 0..2047  (64 tokT * 32 kT)
  int tokT = wid >> 5, kT = wid & 31;
  int l5 = lane & 31, g = lane >> 5;
  const float* src = x + ((size_t)(tokT * 32 + l5) * IND + kT * 16 + g * 8);
  _Float16* dst = wsx + (size_t)(tokT * 32 + kT) * 1024 + lane * 8;
  splitStore8(src, dst);
}

extern "C" __global__ void __launch_bounds__(256)
split_w_k(const float* __restrict__ W1, const float* __restrict__ W2, const float* __restrict__ W3,
          _Float16* __restrict__ wsw) {
  int tid = threadIdx.x, lane = tid & 63;
  int wid = blockIdx.x * 4 + (tid >> 6);     // 0..63999 (100 classes * 640 tiles)
  int c = wid / 640, t = wid % 640;
  int l5 = lane & 31, g = lane >> 5;
  const float* src;
  if (t < 256) {
    src = W1 + ((size_t)(c * 256 + (t >> 5) * 32 + l5) * 512 + (t & 31) * 16 + g * 8);
  } else if (t < 384) {
    int tt = t - 256;
    src = W2 + ((size_t)(c * 256 + (tt >> 4) * 32 + l5) * 256 + (tt & 15) * 16 + g * 8);
  } else {
    int tt = t - 384;
    src = W3 + ((size_t)(c * 512 + (tt >> 4) * 32 + l5) * 256 + (tt & 15) * 16 + g * 8);
  }
  _Float16* dst = wsw + (size_t)(c * 640 + t) * 1024 + lane * 8;
  splitStore8(src, dst);
}

// ---------------------------------------------------------------------------
// Main fused kernel
// ---------------------------------------------------------------------------
struct Frag8 { half8 hi, lo; };
struct FragSet { Frag8 a0, a1, b0, b1; };

__device__ __forceinline__ void ldFrag(Frag8& f, const _Float16* p) {
  f.hi = *(const half8*)(p);
  f.lo = *(const half8*)(p + 512);
}

template<int BS>
__device__ __forceinline__ void ldSet(FragSet& s, const _Float16* a0, const _Float16* a1,
                                      const _Float16* b0, const _Float16* b1, int k) {
  ldFrag(s.a0, a0 + (size_t)k * 1024);
  ldFrag(s.a1, a1 + (size_t)k * 1024);
  ldFrag(s.b0, b0 + (size_t)k * BS);
  ldFrag(s.b1, b1 + (size_t)k * BS);
}

#define MFMA(A, B, C) __builtin_amdgcn_mfma_f32_32x32x16_f16((A), (B), (C), 0, 0, 0)

__device__ __forceinline__ void mmSet(const FragSet& s, f32x16 acc[2][2]) {
  acc[0][0] = MFMA(s.a0.hi, s.b0.hi, acc[0][0]);
  acc[0][0] = MFMA(s.a0.hi, s.b0.lo, acc[0][0]);
  acc[0][0] = MFMA(s.a0.lo, s.b0.hi, acc[0][0]);
  acc[0][1] = MFMA(s.a0.hi, s.b1.hi, acc[0][1]);
  acc[0][1] = MFMA(s.a0.hi, s.b1.lo, acc[0][1]);
  acc[0][1] = MFMA(s.a0.lo, s.b1.hi, acc[0][1]);
  acc[1][0] = MFMA(s.a1.hi, s.b0.hi, acc[1][0]);
  acc[1][0] = MFMA(s.a1.hi, s.b0.lo, acc[1][0]);
  acc[1][0] = MFMA(s.a1.lo, s.b0.hi, acc[1][0]);
  acc[1][1] = MFMA(s.a1.hi, s.b1.hi, acc[1][1]);
  acc[1][1] = MFMA(s.a1.hi, s.b1.lo, acc[1][1]);
  acc[1][1] = MFMA(s.a1.lo, s.b1.hi, acc[1][1]);
}

template<int NK, int BS>
__device__ __forceinline__ void kloop(const _Float16* __restrict__ a0, const _Float16* __restrict__ a1,
                                      const _Float16* b0, const _Float16* b1, f32x16 acc[2][2]) {
  FragSet X, Y;
  ldSet<BS>(X, a0, a1, b0, b1, 0);
#pragma unroll 1
  for (int kp = 0; kp < NK / 2 - 1; ++kp) {
    ldSet<BS>(Y, a0, a1, b0, b1, 2 * kp + 1);
    mmSet(X, acc);
    ldSet<BS>(X, a0, a1, b0, b1, 2 * kp + 2);
    mmSet(Y, acc);
  }
  ldSet<BS>(Y, a0, a1, b0, b1, NK - 1);
  mmSet(X, acc);
  mmSet(Y, acc);
}

// bias + LayerNorm + exact GELU in C-layout regs, then rebuild B-fragments
// for the next GEMM in-register and store to sH. Ends with barrier.
__device__ __forceinline__ void lnGeluFrag(f32x16 acc[2][2],
                                           const float* __restrict__ bias, const float* __restrict__ gam,
                                           const float* __restrict__ bet, int cb,
                                           _Float16* sH, float (*sStat)[64][2],
                                           int w, int l5, int g, int lane) {
  // bias add (row-indexed; same for both token tiles)
#pragma unroll
  for (int mt = 0; mt < 2; ++mt) {
    int ob = cb + (2 * w + mt) * 32 + (g ? 4 : 0);
#pragma unroll
    for (int r = 0; r < 16; ++r) {
      int rr = (r & 3) + 8 * (r >> 2);
      float bb = bias[ob + rr];
      acc[mt][0][r] += bb;
      acc[mt][1][r] += bb;
    }
  }
  // per-token stats over the hidden (row) dim
  float s0 = 0.f, q0 = 0.f, s1 = 0.f, q1 = 0.f;
#pragma unroll
  for (int mt = 0; mt < 2; ++mt)
#pragma unroll
    for (int r = 0; r < 16; ++r) {
      float v0 = acc[mt][0][r]; s0 += v0; q0 += v0 * v0;
      float v1 = acc[mt][1][r]; s1 += v1; q1 += v1 * v1;
    }
  s0 += __shfl_xor(s0, 32, 64); q0 += __shfl_xor(q0, 32, 64);
  s1 += __shfl_xor(s1, 32, 64); q1 += __shfl_xor(q1, 32, 64);
  if (lane < 32) {
    sStat[w][l5][0] = s0;      sStat[w][l5][1] = q0;
    sStat[w][l5 + 32][0] = s1; sStat[w][l5 + 32][1] = q1;
  }
  __syncthreads();   // also guarantees all waves finished reading sH (k-loop done)
  float S0 = 0.f, Q0 = 0.f, S1 = 0.f, Q1 = 0.f;
#pragma unroll
  for (int ww = 0; ww < 4; ++ww) {
    S0 += sStat[ww][l5][0];      Q0 += sStat[ww][l5][1];
    S1 += sStat[ww][l5 + 32][0]; Q1 += sStat[ww][l5 + 32][1];
  }
  float mu0 = S0 * (1.f / HIDD), var0 = Q0 * (1.f / HIDD) - mu0 * mu0;
  float rs0 = rsqrtf(var0 + 1e-5f);
  float mu1 = S1 * (1.f / HIDD), var1 = Q1 * (1.f / HIDD) - mu1 * mu1;
  float rs1 = rsqrtf(var1 + 1e-5f);
  // gamma/beta + exact GELU
#pragma unroll
  for (int mt = 0; mt < 2; ++mt) {
    int ob = cb + (2 * w + mt) * 32 + (g ? 4 : 0);
#pragma unroll
    for (int r = 0; r < 16; ++r) {
      int rr = (r & 3) + 8 * (r >> 2);
      float gm = gam[ob + rr], bt = bet[ob + rr];
      float v0 = (acc[mt][0][r] - mu0) * rs0 * gm + bt;
      acc[mt][0][r] = 0.5f * v0 * (1.f + erff(v0 * 0.70710678118654752f));
      float v1 = (acc[mt][1][r] - mu1) * rs1 * gm + bt;
      acc[mt][1][r] = 0.5f * v1 * (1.f + erff(v1 * 0.70710678118654752f));
    }
  }
  // rebuild B-fragments for the next GEMM (in-register transpose).
  // Thread (g) holds rows {0..3,8..11}+4g (g=0) / {4..7,12..15}+4g-4 ... i.e.
  // g=0: {0-3,8-11,16-19,24-27}, g=1: {4-7,12-15,20-23,28-31}. For subtile kt
  // (rows kt*16..kt*16+15): send partner the pair IT needs, keep own pair.
#pragma unroll
  for (int mt = 0; mt < 2; ++mt) {
#pragma unroll
    for (int nt = 0; nt < 2; ++nt) {
      unsigned P[8], L[8];
#pragma unroll
      for (int i = 0; i < 8; ++i) {
        float a0 = acc[mt][nt][2 * i], a1 = acc[mt][nt][2 * i + 1];
        half2v ph = __builtin_amdgcn_cvt_pkrtz(a0, a1);
        half2v pl = __builtin_amdgcn_cvt_pkrtz(a0 - (float)ph[0], a1 - (float)ph[1]);
        P[i] = h2u(ph); L[i] = h2u(pl);
      }
#pragma unroll
      for (int kt = 0; kt < 2; ++kt) {
        // what the PARTNER needs from this lane:
        unsigned s0h = g ? P[4 * kt + 0] : P[4 * kt + 2];
        unsigned s1h = g ? P[4 * kt + 1] : P[4 * kt + 3];
        unsigned s0l = g ? L[4 * kt + 0] : L[4 * kt + 2];
        unsigned s1l = g ? L[4 * kt + 1] : L[4 * kt + 3];
        unsigned r0h = __shfl_xor(s0h, 32, 64);
        unsigned r1h = __shfl_xor(s1h, 32, 64);
        unsigned r0l = __shfl_xor(s0l, 32, 64);
        unsigned r1l = __shfl_xor(s1l, 32, 64);
        // g=0 slots j=0..7 -> rows kt*16 + 0..7 = [own P0,P1 | recv P0,P1]
        // g=1 slots j=0..7 -> rows kt*16 + 8..15 = [recv P2,P3 | own P2,P3]
        unsigned hv0 = g ? r0h : P[4 * kt + 0];
        unsigned hv1 = g ? r1h : P[4 * kt + 1];
        unsigned hv2 = g ? P[4 * kt + 2] : r0h;
        unsigned hv3 = g ? P[4 * kt + 3] : r1h;
        unsigned lv0 = g ? r0l : L[4 * kt + 0];
        unsigned lv1 = g ? r1l : L[4 * kt + 1];
        unsigned lv2 = g ? L[4 * kt + 2] : r0l;
        unsigned lv3 = g ? L[4 * kt + 3] : r1l;
        int kT = 4 * w + 2 * mt + kt;
        _Float16* dst = sH + (size_t)((kT * 2 + nt) * 2) * 512 + lane * 8;
        *(half8*)dst = u4h8(hv0, hv1, hv2, hv3);
        *(half8*)(dst + 512) = u4h8(lv0, lv1, lv2, lv3);
      }
    }
  }
  __syncthreads();
}

extern "C" __global__ void __launch_bounds__(256, 2)
moe_f16(const _Float16* __restrict__ wsx, const _Float16* __restrict__ wsw,
        const float* __restrict__ b1, const float* __restrict__ g1, const float* __restrict__ be1,
        const float* __restrict__ b2, const float* __restrict__ g2, const float* __restrict__ be2,
        const float* __restrict__ b3, const float* __restrict__ anchors,
        float* __restrict__ out_dist, float* __restrict__ out_sim) {
  __shared__ _Float16 sH[32768];        // 16 kT x 2 tokT x (hi,lo) x 512 halves = 64 KB
  __shared__ float sStat[4][64][2];

  const int tid = threadIdx.x;
  const int lane = tid & 63, w = tid >> 6;
  const int l5 = lane & 31, g = lane >> 5;

  // bijective XCD swizzle: one class's 32 token-tiles stay on one XCD
  const int p0 = blockIdx.x;            // 3200 = 8 * 400
  const int lg = (p0 & 7) * 400 + (p0 >> 3);
  const int c = lg >> 5;
  const int tokT2 = lg & 31;            // 64-token tile

  // anchor 1/||a||
  {
    float a0 = anchors[c * OUTD + tid];
    float a1 = anchors[c * OUTD + 256 + tid];
    float aa = a0 * a0 + a1 * a1;
#pragma unroll
    for (int m = 1; m <= 32; m <<= 1) aa += __shfl_xor(aa, m, 64);
    if (lane == 0) sStat[w][0][0] = aa;
  }
  __syncthreads();
  const float rinv = rsqrtf(sStat[0][0][0] + sStat[1][0][0] + sStat[2][0][0] + sStat[3][0][0]);
  __syncthreads();

  const _Float16* wc = wsw + (size_t)c * CLS_STRIDE + lane * 8;
  const _Float16* xB0 = wsx + (size_t)((tokT2 * 2 + 0) * 32) * 1024 + lane * 8;
  const _Float16* xB1 = wsx + (size_t)((tokT2 * 2 + 1) * 32) * 1024 + lane * 8;
  const _Float16* sB0 = sH + 0 * 1024 + lane * 8;
  const _Float16* sB1 = sH + 1 * 1024 + lane * 8;

  f32x16 acc[2][2];

  // ---- phase 1: h1 = W1 . x^T   (M=256 rows split over waves, N=64 tokens)
  acc[0][0] = fzero16(); acc[0][1] = fzero16(); acc[1][0] = fzero16(); acc[1][1] = fzero16();
  kloop<32, 1024>(wc + (size_t)(2 * w + 0) * 32 * 1024,
                  wc + (size_t)(2 * w + 1) * 32 * 1024, xB0, xB1, acc);
  lnGeluFrag(acc, b1, g1, be1, c * HIDD, sH, sStat, w, l5, g, lane);

  // ---- phase 2: h2 = W2 . h1^T
  acc[0][0] = fzero16(); acc[0][1] = fzero16(); acc[1][0] = fzero16(); acc[1][1] = fzero16();
  kloop<16, 2048>(wc + W2_OFF + (size_t)(2 * w + 0) * 16 * 1024,
                  wc + W2_OFF + (size_t)(2 * w + 1) * 16 * 1024, sB0, sB1, acc);
  lnGeluFrag(acc, b2, g2, be2, c * HIDD, sH, sStat, w, l5, g, lane);

  // ---- phase 3: t = W3 . h2^T (+b3), two 256-row passes; cosine geometry
  float pdot0 = 0.f, psq0 = 0.f, pdot1 = 0.f, psq1 = 0.f;
#pragma unroll 1
  for (int p = 0; p < 2; ++p) {
    acc[0][0] = fzero16(); acc[0][1] = fzero16(); acc[1][0] = fzero16(); acc[1][1] = fzero16();
    kloop<16, 2048>(wc + W3_OFF + (size_t)(8 * p + 2 * w + 0) * 16 * 1024,
                    wc + W3_OFF + (size_t)(8 * p + 2 * w + 1) * 16 * 1024, sB0, sB1, acc);
#pragma unroll
    for (int mt = 0; mt < 2; ++mt) {
      int ob = c * OUTD + (8 * p + 2 * w + mt) * 32 + (g ? 4 : 0);
#pragma unroll
      for (int r = 0; r < 16; ++r) {
        int rr = (r & 3) + 8 * (r >> 2);
        float bb = b3[ob + rr];
        float av = anchors[ob + rr] * rinv;
        float t0 = acc[mt][0][r] + bb;
        pdot0 = fmaf(t0, av, pdot0); psq0 = fmaf(t0, t0, psq0);
        float t1 = acc[mt][1][r] + bb;
        pdot1 = fmaf(t1, av, pdot1); psq1 = fmaf(t1, t1, psq1);
      }
    }
  }
  pdot0 += __shfl_xor(pdot0, 32, 64); psq0 += __shfl_xor(psq0, 32, 64);
  pdot1 += __shfl_xor(pdot1, 32, 64); psq1 += __shfl_xor(psq1, 32, 64);
  if (lane < 32) {
    sStat[w][l5][0] = pdot0;      sStat[w][l5][1] = psq0;
    sStat[w][l5 + 32][0] = pdot1; sStat[w][l5 + 32][1] = psq1;
  }
  __syncthreads();
  if (tid < 64) {
    float dd = 0.f, qq = 0.f;
#pragma unroll
    for (int ww = 0; ww < 4; ++ww) { dd += sStat[ww][tid][0]; qq += sStat[ww][tid][1]; }
    float s = dd * rsqrtf(qq);
    float d = sqrtf(fmaxf(2.f - 2.f * s, 0.f));
    int t = tokT2 * 64 + tid;
    out_dist[(size_t)t * NCLS + c] = d;
    out_sim[(size_t)t * NCLS + c] = s;
  }
}

extern "C" __global__ void __launch_bounds__(256)
argmin_routed(const float* __restrict__ dist, float* __restrict__ routed) {
  int b = blockIdx.x * blockDim.x + threadIdx.x;
  if (b >= NTOK) return;
  const float* d = dist + (size_t)b * NCLS;
  float best = d[0];
  int bi = 0;
#pragma unroll 1
  for (int cc = 1; cc < NCLS; ++cc) {
    float v = d[cc];
    if (v < best) { best = v; bi = cc; }
  }
  routed[b] = (float)bi;
}

// ===========================================================================
// fp32 fallback (round-1 kernel, validated) — used only if ws is too small.
// ===========================================================================
#define BT   64
#define KT   16
#define SA   68
#define SWS  260

__device__ __forceinline__ float4 ld4(const float* p) { return *(const float4*)p; }

__device__ __forceinline__ void loadW4(float4 wr[4], const float* __restrict__ gp, int k0) {
#pragma unroll
  for (int i = 0; i < 4; ++i) wr[i] = ld4(gp + k0 + 4 * i);
}

__device__ __forceinline__ void storeW4(float* sW, const float4 wr[4], int t) {
#pragma unroll
  for (int i = 0; i < 4; ++i) {
    sW[(4 * i + 0) * SWS + t] = wr[i].x;
    sW[(4 * i + 1) * SWS + t] = wr[i].y;
    sW[(4 * i + 2) * SWS + t] = wr[i].z;
    sW[(4 * i + 3) * SWS + t] = wr[i].w;
  }
}

__device__ __forceinline__ void storeX4(float* sX, const float4 xr, int xtok, int xkh) {
  sX[(xkh * 4 + 0) * SA + xtok] = xr.x;
  sX[(xkh * 4 + 1) * SA + xtok] = xr.y;
  sX[(xkh * 4 + 2) * SA + xtok] = xr.z;
  sX[(xkh * 4 + 3) * SA + xtok] = xr.w;
}

__device__ __forceinline__ void fma_chunk(const float* __restrict__ A, const float* __restrict__ sW,
                                          int ty8, int o_lo, int o_hi, float acc[8][8]) {
#pragma unroll
  for (int k = 0; k < KT; ++k) {
    const float* a = A + k * SA + ty8;
    float4 t0 = ld4(a);
    float4 t1 = ld4(a + 4);
    const float* wp = sW + k * SWS;
    float4 w0 = ld4(wp + o_lo);
    float4 w1 = ld4(wp + o_hi);
    float tv[8] = {t0.x, t0.y, t0.z, t0.w, t1.x, t1.y, t1.z, t1.w};
    float wv[8] = {w0.x, w0.y, w0.z, w0.w, w1.x, w1.y, w1.z, w1.w};
#pragma unroll
    for (int j = 0; j < 8; ++j)
#pragma unroll
      for (int i = 0; i < 8; ++i)
        acc[j][i] = fmaf(tv[j], wv[i], acc[j][i]);
  }
}

template <int NC>
__device__ __forceinline__ void gemm_phase(const float* __restrict__ gRow, const float* __restrict__ A,
                                           float* sW, int tid, int ty8, int o_lo, int o_hi,
                                           float acc[8][8]) {
  float4 wr[4];
  loadW4(wr, gRow, 0);
  __syncthreads();
  storeW4(sW, wr, tid);
  __syncthreads();
#pragma unroll 1
  for (int kc = 0; kc < NC; ++kc) {
    if (kc + 1 < NC) loadW4(wr, gRow, (kc + 1) * KT);
    fma_chunk(A + kc * KT * SA, sW, ty8, o_lo, o_hi, acc);
    if (kc + 1 < NC) {
      __syncthreads();
      storeW4(sW, wr, tid);
      __syncthreads();
    }
  }
}

__device__ __forceinline__ void gemm_phase1(const float* __restrict__ gWrow, const float* __restrict__ gXrow,
                                            float* sW, float* sX, int tid, int xtok, int xkh,
                                            int ty8, int o_lo, int o_hi, float acc[8][8]) {
  float4 wr[4];
  float4 xr;
  loadW4(wr, gWrow, 0);
  xr = ld4(gXrow);
  __syncthreads();
  storeW4(sW, wr, tid);
  storeX4(sX, xr, xtok, xkh);
  __syncthreads();
#pragma unroll 1
  for (int kc = 0; kc < IND / KT; ++kc) {
    if (kc + 1 < IND / KT) {
      loadW4(wr, gWrow, (kc + 1) * KT);
      xr = ld4(gXrow + (kc + 1) * KT);
    }
    fma_chunk(sX, sW, ty8, o_lo, o_hi, acc);
    if (kc + 1 < IND / KT) {
      __syncthreads();
      storeW4(sW, wr, tid);
      storeX4(sX, xr, xtok, xkh);
      __syncthreads();
    }
  }
}

__device__ __forceinline__ void ln_gelu_store(float acc[8][8], const float* __restrict__ bias,
                                              const float* __restrict__ gam, const float* __restrict__ bet,
                                              int cb, float* sHd, int ty8, int o_lo, int o_hi) {
  float4 q0 = ld4(bias + cb + o_lo), q1 = ld4(bias + cb + o_hi);
  float bv[8] = {q0.x, q0.y, q0.z, q0.w, q1.x, q1.y, q1.z, q1.w};
  float4 g0 = ld4(gam + cb + o_lo), g1q = ld4(gam + cb + o_hi);
  float gv[8] = {g0.x, g0.y, g0.z, g0.w, g1q.x, g1q.y, g1q.z, g1q.w};
  float4 e0 = ld4(bet + cb + o_lo), e1 = ld4(bet + cb + o_hi);
  float ev[8] = {e0.x, e0.y, e0.z, e0.w, e1.x, e1.y, e1.z, e1.w};

  float sum[8], ssq[8];
#pragma unroll
  for (int j = 0; j < 8; ++j) {
    float s = 0.f, q = 0.f;
#pragma unroll
    for (int i = 0; i < 8; ++i) {
      float v = acc[j][i] + bv[i];
      acc[j][i] = v;
      s += v;
      q += v * v;
    }
    sum[j] = s;
    ssq[j] = q;
  }
#pragma unroll
  for (int m = 1; m <= 16; m <<= 1) {
#pragma unroll
    for (int j = 0; j < 8; ++j) {
      sum[j] += __shfl_xor(sum[j], m, 64);
      ssq[j] += __shfl_xor(ssq[j], m, 64);
    }
  }
#pragma unroll
  for (int j = 0; j < 8; ++j) {
    float mu = sum[j] * (1.f / HIDD);
    float var = ssq[j] * (1.f / HIDD) - mu * mu;
    float rs = rsqrtf(var + 1e-5f);
#pragma unroll
    for (int i = 0; i < 8; ++i) {
      float v = (acc[j][i] - mu) * rs * gv[i] + ev[i];
      acc[j][i] = 0.5f * v * (1.f + erff(v * 0.70710678118654752f));
    }
  }
#pragma unroll
  for (int i = 0; i < 8; ++i) {
    int o = (i < 4) ? (o_lo + i) : (o_hi + (i - 4));
    float4 pq0, pq1;
    pq0.x = acc[0][i]; pq0.y = acc[1][i]; pq0.z = acc[2][i]; pq0.w = acc[3][i];
    pq1.x = acc[4][i]; pq1.y = acc[5][i]; pq1.z = acc[6][i]; pq1.w = acc[7][i];
    *(float4*)(sHd + o * SA + ty8) = pq0;
    *(float4*)(sHd + o * SA + ty8 + 4) = pq1;
  }
}

extern "C" __global__ void __launch_bounds__(256)
moe_fused_f32(const float* __restrict__ x, const float* __restrict__ W1, const float* __restrict__ b1,
              const float* __restrict__ g1, const float* __restrict__ be1,
              const float* __restrict__ W2, const float* __restrict__ b2,
              const float* __restrict__ g2, const float* __restrict__ be2,
              const float* __restrict__ W3, const float* __restrict__ b3,
              const float* __restrict__ anchors,
              float* __restrict__ out_dist, float* __restrict__ out_sim) {
  __shared__ __align__(16) float sW[KT * SWS];
  __shared__ __align__(16) float sX[KT * SA];
  __shared__ __align__(16) float sHd[HIDD * SA];
  __shared__ float sRed[4];

  const int tid = threadIdx.x;
  const int tx = tid & 31, ty = tid >> 5;
  const int ty8 = ty * 8;
  const int o_lo = 4 * tx, o_hi = 128 + 4 * tx;
  const int c = blockIdx.y;
  const int tb = blockIdx.x * BT;

  {
    float v0 = anchors[c * OUTD + tid];
    float v1 = anchors[c * OUTD + 256 + tid];
    float aa = v0 * v0 + v1 * v1;
#pragma unroll
    for (int m = 1; m <= 32; m <<= 1) aa += __shfl_xor(aa, m, 64);
    if ((tid & 63) == 0) sRed[tid >> 6] = aa;
  }
  __syncthreads();
  const float rinv = rsqrtf(sRed[0] + sRed[1] + sRed[2] + sRed[3]);

  float acc[8][8];

#pragma unroll
  for (int j = 0; j < 8; ++j)
#pragma unroll
    for (int i = 0; i < 8; ++i) acc[j][i] = 0.f;

  gemm_phase1(W1 + (size_t)(c * HIDD + tid) * IND,
              x + (size_t)(tb + (tid & 63)) * IND + (tid >> 6) * 4,
              sW, sX, tid, tid & 63, tid >> 6, ty8, o_lo, o_hi, acc);
  ln_gelu_store(acc, b1, g1, be1, c * HIDD, sHd, ty8, o_lo, o_hi);

#pragma unroll
  for (int j = 0; j < 8; ++j)
#pragma unroll
    for (int i = 0; i < 8; ++i) acc[j][i] = 0.f;

  gemm_phase<HIDD / KT>(W2 + (size_t)(c * HIDD + tid) * HIDD, sHd, sW, tid, ty8, o_lo, o_hi, acc);
  __syncthreads();
  ln_gelu_store(acc, b2, g2, be2, c * HIDD, sHd, ty8, o_lo, o_hi);

  float pdot[8], psq[8];
#pragma unroll
  for (int j = 0; j < 8; ++j) { pdot[j] = 0.f; psq[j] = 0.f; }

#pragma unroll 1
  for (int p = 0; p < 2; ++p) {
#pragma unroll
    for (int j = 0; j < 8; ++j)
#pragma unroll
      for (int i = 0; i < 8; ++i) acc[j][i] = 0.f;

    gemm_phase<HIDD / KT>(W3 + (size_t)(c * OUTD + p * 256 + tid) * HIDD, sHd, sW, tid, ty8, o_lo, o_hi, acc);

    const int ob = c * OUTD + p * 256;
    float4 q0 = ld4(b3 + ob + o_lo), q1 = ld4(b3 + ob + o_hi);
    float bv[8] = {q0.x, q0.y, q0.z, q0.w, q1.x, q1.y, q1.z, q1.w};
    float4 a0 = ld4(anchors + ob + o_lo), a1 = ld4(anchors + ob + o_hi);
    float av[8] = {a0.x * rinv, a0.y * rinv, a0.z * rinv, a0.w * rinv,
                   a1.x * rinv, a1.y * rinv, a1.z * rinv, a1.w * rinv};
#pragma unroll
    for (int j = 0; j < 8; ++j)
#pragma unroll
      for (int i = 0; i < 8; ++i) {
        float t = acc[j][i] + bv[i];
        pdot[j] = fmaf(t, av[i], pdot[j]);
        psq[j] = fmaf(t, t, psq[j]);
      }
  }

#pragma unroll
  for (int m = 1; m <= 16; m <<= 1) {
#pragma unroll
    for (int j = 0; j < 8; ++j) {
      pdot[j] += __shfl_xor(pdot[j], m, 64);
      psq[j] += __shfl_xor(psq[j], m, 64);
    }
  }
  if (tx < 8) {
    float pd = 0.f, pq = 1.f;
#pragma unroll
    for (int j = 0; j < 8; ++j)
      if (tx == j) { pd = pdot[j]; pq = psq[j]; }
    const int b = tb + ty8 + tx;
    float s = pd * rsqrtf(pq);
    float d = sqrtf(fmaxf(2.f - 2.f * s, 0.f));
    out_dist[(size_t)b * NCLS + c] = d;
    out_sim[(size_t)b * NCLS + c] = s;
  }
}

// ===========================================================================
extern "C" void kernel_launch(void* const* d_in, const int* in_sizes, int n_in,
                              void* d_out, int out_size, void* d_ws, size_t ws_size,
                              hipStream_t stream) {
  const float* x = (const float*)d_in[0];
  const float* W1 = (const float*)d_in[1];
  const float* b1 = (const float*)d_in[2];
  const float* g1 = (const float*)d_in[3];
  const float* be1 = (const float*)d_in[4];
  const float* W2 = (const float*)d_in[5];
  const float* b2 = (const float*)d_in[6];
  const float* g2 = (const float*)d_in[7];
  const float* be2 = (const float*)d_in[8];
  const float* W3 = (const float*)d_in[9];
  const float* b3 = (const float*)d_in[10];
  const float* anchors = (const float*)d_in[11];

  float* out = (float*)d_out;
  float* out_routed = out;
  float* out_dist = out + NTOK;
  float* out_sim = out + NTOK + NTOK * NCLS;

  if (ws_size >= WS_NEED) {
    _Float16* wsh = (_Float16*)d_ws;
    split_x_k<<<512, 256, 0, stream>>>(x, wsh);
    split_w_k<<<16000, 256, 0, stream>>>(W1, W2, W3, wsh + WSX_HALVES);
    moe_f16<<<3200, 256, 0, stream>>>(wsh, wsh + WSX_HALVES,
                                      b1, g1, be1, b2, g2, be2, b3, anchors,
                                      out_dist, out_sim);
  } else {
    dim3 grid(NTOK / BT, NCLS);
    moe_fused_f32<<<grid, 256, 0, stream>>>(x, W1, b1, g1, be1, W2, b2, g2, be2, W3, b3,
                                            anchors, out_dist, out_sim);
  }
  argmin_routed<<<NTOK / 256, 256, 0, stream>>>(out_dist, out_routed);
}